// Round 2
// baseline (542.189 us; speedup 1.0000x reference)
//
#include <hip/hip_runtime.h>
#include <string.h>

typedef __bf16 bf16x8 __attribute__((ext_vector_type(8)));
typedef float f32x4 __attribute__((ext_vector_type(4)));
typedef unsigned short u16;
typedef u16 u16x8 __attribute__((ext_vector_type(8)));

#define NB 16     // batch
#define CD 512    // channels
#define NN 4096   // hw
#define O3 1536   // 3*hidden

__device__ __forceinline__ u16 f2bf(float f) {
    union { float f; unsigned int u; } v; v.f = f;
    unsigned int r = v.u + 0x7fffu + ((v.u >> 16) & 1u);
    return (u16)(r >> 16);
}
__device__ __forceinline__ float bf2f(u16 s) {
    union { unsigned int u; float f; } v; v.u = ((unsigned int)s) << 16;
    return v.f;
}

__device__ __forceinline__ void gl2lds16(const u16* g, u16* l) {
    __builtin_amdgcn_global_load_lds(
        (const void __attribute__((address_space(1)))*)g,
        (void __attribute__((address_space(3)))*)l,
        16, 0, 0);
}

// ---------------- convert w_qkv fp32 -> bf16 (row-major [1536][512]) ----------
__global__ void k_convert(const float* __restrict__ in, u16* __restrict__ out, int n) {
    int i = blockIdx.x * 256 + threadIdx.x;
    if (i < n) out[i] = f2bf(in[i]);
}

// ---------------- transpose x[b][c][n] fp32 -> xt[b][n][c] bf16, 64x64 tiles --
__global__ __launch_bounds__(256) void k_transpose_x(const float* __restrict__ x,
                                                     u16* __restrict__ xt) {
    __shared__ float tile[64][65];
    const int b = blockIdx.y;
    const int ntile = blockIdx.x & 63;   // 4096/64
    const int ctile = blockIdx.x >> 6;   // 512/64
    const int t = threadIdx.x;
    const int r = t >> 2;                // 0..63 (row)
    const int q = t & 3;                 // 4 threads per row

    const float* xb = x + ((size_t)b * CD + ctile * 64 + r) * NN + ntile * 64;
#pragma unroll
    for (int j = 0; j < 4; ++j) {
        float4 v = *(const float4*)&xb[q * 16 + j * 4];
        tile[r][q * 16 + j * 4 + 0] = v.x;
        tile[r][q * 16 + j * 4 + 1] = v.y;
        tile[r][q * 16 + j * 4 + 2] = v.z;
        tile[r][q * 16 + j * 4 + 3] = v.w;
    }
    __syncthreads();
    u16* xtb = xt + ((size_t)b * NN + ntile * 64 + r) * CD + ctile * 64 + q * 16;
    u16x8 o0, o1;
#pragma unroll
    for (int j = 0; j < 8; ++j) {
        o0[j] = f2bf(tile[q * 16 + j][r]);
        o1[j] = f2bf(tile[q * 16 + 8 + j][r]);
    }
    *(u16x8*)&xtb[0] = o0;
    *(u16x8*)&xtb[8] = o1;
}

// =============================================================================
// 256x256 8-phase bf16 GEMM core (T2 swizzle + T3/T4 counted vmcnt + T5 setprio)
// Loop identical to the verified R1 kernel; LDS buffer passed in so the caller
// can reuse the 128 KiB for the epilogue transpose after the final drain.
// =============================================================================

__device__ __forceinline__ void lda8(const u16* p, bf16x8 (&aa)[4][2],
                                     int aoff, int sw0, int sw1) {
#pragma unroll
    for (int mi = 0; mi < 4; ++mi) {
        aa[mi][0] = *(const bf16x8*)&p[aoff + mi * 1024 + sw0];
        aa[mi][1] = *(const bf16x8*)&p[aoff + mi * 1024 + sw1];
    }
}

__device__ __forceinline__ void ldb4(const u16* p, bf16x8 (&bb)[2][2],
                                     int boff, int sw0, int sw1) {
#pragma unroll
    for (int ni = 0; ni < 2; ++ni) {
        bb[ni][0] = *(const bf16x8*)&p[boff + ni * 1024 + sw0];
        bb[ni][1] = *(const bf16x8*)&p[boff + ni * 1024 + sw1];
    }
}

__device__ __forceinline__ void mfma16(bf16x8 (&aa)[4][2], bf16x8 (&bb)[2][2],
                                       f32x4 (&ac)[4][2]) {
    __builtin_amdgcn_s_setprio(1);
#pragma unroll
    for (int mi = 0; mi < 4; ++mi)
#pragma unroll
        for (int ni = 0; ni < 2; ++ni) {
            ac[mi][ni] = __builtin_amdgcn_mfma_f32_16x16x32_bf16(
                aa[mi][0], bb[ni][0], ac[mi][ni], 0, 0, 0);
            ac[mi][ni] = __builtin_amdgcn_mfma_f32_16x16x32_bf16(
                aa[mi][1], bb[ni][1], ac[mi][ni], 0, 0, 0);
        }
    __builtin_amdgcn_s_setprio(0);
}

#define MIDBAR() do { \
    asm volatile("" ::: "memory"); \
    __builtin_amdgcn_s_barrier(); \
    asm volatile("s_waitcnt lgkmcnt(0)" ::: "memory"); \
} while (0)

#define ENDBAR() do { \
    asm volatile("" ::: "memory"); \
    __builtin_amdgcn_s_barrier(); \
    asm volatile("" ::: "memory"); \
} while (0)

__device__ __forceinline__ void gemm256_core(u16* __restrict__ smem,
                                             const u16* __restrict__ Abase,
                                             const u16* __restrict__ Bbase,
                                             f32x4 (&acc)[2][2][4][2]) {
    const int t = threadIdx.x;
    const int lane = t & 63;
    const int w = t >> 6;
    const int l15 = lane & 15, quad = lane >> 4;
    const int r0 = t >> 3;                       // staging row 0..63 (issue 0)
    const int sg = ((t & 7) ^ (r0 & 7)) * 8;     // pre-swizzled source k-offset (elems)
    const int aoff = ((w >> 2) * 64 + l15) * 64; // wave m-offset within quadrant half
    const int boff = ((w & 3) * 32 + l15) * 64;  // wave n-offset within quadrant half
    const int sw0 = ((0 + quad) ^ (l15 & 7)) * 8;  // swizzled read slot, kstep 0
    const int sw1 = ((4 + quad) ^ (l15 & 7)) * 8;  // swizzled read slot, kstep 1

    auto ldsAt = [&](int s, int op, int half) -> u16* {
        return smem + (size_t)(((s * 2 + op) * 2 + half) * 8192);
    };

    auto stage = [&](int op, int half, int tau) {
        const u16* s = (op ? Bbase : Abase)
                       + (size_t)(half * 128 + r0) * CD + tau * 64 + sg;
        u16* d = ldsAt(tau & 1, op, half) + t * 8;
        gl2lds16(s, d);                          // rows 0..63 of the half
        gl2lds16(s + (size_t)64 * CD, d + 4096); // rows 64..127
    };

    // prologue: tile 0 fully + A0/B0 of tile 1 (matches steady-state in-flight set)
    stage(0, 0, 0); stage(1, 0, 0); stage(1, 1, 0); stage(0, 1, 0);
    stage(0, 0, 1); stage(1, 0, 1);
    asm volatile("s_waitcnt vmcnt(4)" ::: "memory");  // tile 0 complete
    ENDBAR();

    bf16x8 aa[4][2], bb0[2][2], bb1[2][2];
    for (int kt = 0; kt < 8; ++kt) {
        const int s = kt & 1;
        // ---- phase 0: Q(0,0) — 12 ds_read_b128
        lda8(ldsAt(s, 0, 0), aa, aoff, sw0, sw1);
        ldb4(ldsAt(s, 1, 0), bb0, boff, sw0, sw1);
        if (kt <= 6) stage(1, 1, kt + 1);
        MIDBAR();
        mfma16(aa, bb0, acc[0][0]);
        ENDBAR();
        // ---- phase 1: Q(0,1) — reuse aa, 4 reads
        ldb4(ldsAt(s, 1, 1), bb1, boff, sw0, sw1);
        if (kt <= 6) stage(0, 1, kt + 1);
        MIDBAR();
        mfma16(aa, bb1, acc[0][1]);
        ENDBAR();
        // ---- phase 2: Q(1,0) — reuse bb0, 8 reads
        lda8(ldsAt(s, 0, 1), aa, aoff, sw0, sw1);
        if (kt <= 5) stage(0, 0, kt + 2);
        MIDBAR();
        mfma16(aa, bb0, acc[1][0]);
        ENDBAR();
        // ---- phase 3: Q(1,1) — all operands in regs, 0 reads
        if (kt <= 5) stage(1, 0, kt + 2);
        MIDBAR();
        mfma16(aa, bb1, acc[1][1]);
        if (kt == 6)      asm volatile("s_waitcnt vmcnt(0)" ::: "memory"); // final drain
        else if (kt < 6)  asm volatile("s_waitcnt vmcnt(4)" ::: "memory"); // tile kt+1 ready
        ENDBAR();
    }
    // after final ENDBAR all LDS reads and global_load_lds writes are complete:
    // callers may reuse smem for the epilogue.
}

// ---------------- GEMM1: qkv = Wqkv(1536x512) @ X_b(512x4096) -----------------
// m-tiles of 256 align with sections: mt 0-1 -> Q, 2-3 -> K, 4-5 -> V.
// Epilogue: LDS transpose (XOR-granule swizzled) -> fully coalesced stores.
__global__ __launch_bounds__(512, 2) void k_gemm1(
        const u16* __restrict__ A, const u16* __restrict__ Bt,
        u16* __restrict__ qt, u16* __restrict__ kbuf, u16* __restrict__ vbuf) {
    __shared__ __align__(16) u16 smem[65536];   // 128 KiB: loop dbuf, then C-tile
    const int gid = blockIdx.x;                 // 1536 blocks = 8 XCD * 192
    const int u = (gid & 7) * 192 + (gid >> 3);
    const int mt = u % 6;                       // 6 consecutive share B-panel on one XCD
    const int bn = u / 6;
    const int b = bn >> 4;
    const int nt = bn & 15;
    const int t = threadIdx.x;
    const int lane = t & 63, w = t >> 6;
    const int l15 = lane & 15, quad = lane >> 4;

    f32x4 acc[2][2][4][2] = {};
    gemm256_core(smem, A + (size_t)(mt * 256) * CD,
                 Bt + ((size_t)b * NN + nt * 256) * CD, acc);

    const int sec = mt >> 1;                    // 0=Q 1=K 2=V
    const int lrb = mt * 256 - sec * 512;
    const int g = t & 63;

    if (sec == 0) {
        // Csh[n][m] bf16, m-granule (4 u16) swizzled by n&7
#pragma unroll
        for (int qm = 0; qm < 2; ++qm)
#pragma unroll
        for (int mi = 0; mi < 4; ++mi) {
            const int ml = qm * 128 + (w >> 2) * 64 + mi * 16 + quad * 4;
            const int gm = ml >> 2;
#pragma unroll
            for (int qn = 0; qn < 2; ++qn)
#pragma unroll
            for (int ni = 0; ni < 2; ++ni) {
                const int nl = qn * 128 + (w & 3) * 32 + ni * 16 + l15;
                f32x4 v = acc[qm][qn][mi][ni];
                ushort4 pk;
                pk.x = f2bf(v[0]); pk.y = f2bf(v[1]);
                pk.z = f2bf(v[2]); pk.w = f2bf(v[3]);
                *(ushort4*)&smem[nl * 256 + ((gm ^ (nl & 7)) << 2)] = pk;
            }
        }
        __syncthreads();
#pragma unroll 8
        for (int i = 0; i < 32; ++i) {
            const int n2 = i * 8 + (t >> 6);
            ushort4 pv = *(const ushort4*)&smem[n2 * 256 + ((g ^ (n2 & 7)) << 2)];
            *(ushort4*)&qt[((size_t)b * NN + nt * 256 + n2) * CD + mt * 256 + g * 4] = pv;
        }
    } else {
        // Csh[m][n] bf16, n-granule (4 u16) swizzled by m&7
        u16* dst = (sec == 1) ? kbuf : vbuf;
#pragma unroll
        for (int qm = 0; qm < 2; ++qm)
#pragma unroll
        for (int mi = 0; mi < 4; ++mi) {
            const int ml = qm * 128 + (w >> 2) * 64 + mi * 16 + quad * 4;
#pragma unroll
            for (int qn = 0; qn < 2; ++qn)
#pragma unroll
            for (int ni = 0; ni < 2; ++ni) {
                const int nl = qn * 128 + (w & 3) * 32 + ni * 16 + l15;
                const int gn = nl >> 2, nj = nl & 3;
                f32x4 v = acc[qm][qn][mi][ni];
#pragma unroll
                for (int r = 0; r < 4; ++r) {
                    const int m = ml + r;
                    smem[m * 256 + ((gn ^ (m & 7)) << 2) + nj] = f2bf(v[r]);
                }
            }
        }
        __syncthreads();
#pragma unroll 8
        for (int i = 0; i < 32; ++i) {
            const int m2 = i * 8 + (t >> 6);
            ushort4 pv = *(const ushort4*)&smem[m2 * 256 + ((g ^ (m2 & 7)) << 2)];
            *(ushort4*)&dst[((size_t)(b * 512 + lrb + m2)) * NN + nt * 256 + g * 4] = pv;
        }
    }
}

// -------- fused exp + context: ctxT[bh][d][c] += sum_n exp(K[c][n]) V[d][n] ---
__global__ __launch_bounds__(256) void k_ctx(const u16* __restrict__ kbuf,
                                             const u16* __restrict__ vbuf,
                                             float* __restrict__ ctxT,
                                             float* __restrict__ lsum) {
    const int bh = blockIdx.y;           // 0..127
    const int chunk = blockIdx.x;        // 0..3, 1024 n each
    const int t = threadIdx.x, lane = t & 63, w = t >> 6;
    const int l15 = lane & 15, quad = lane >> 4;
    const int cb = w * 16;               // wave's 16 c-rows

    const u16* krow = kbuf + (size_t)(bh * 64 + cb + l15) * NN;
    const u16* vb   = vbuf + (size_t)bh * 64 * NN;

    f32x4 acc[4] = {};
    float ls = 0.f;
    for (int i = 0; i < 32; ++i) {
        int n0 = chunk * 1024 + i * 32 + quad * 8;
        u16x8 ku = *(const u16x8*)&krow[n0];
        u16x8 afu;
#pragma unroll
        for (int jj = 0; jj < 8; ++jj) {
            float ev = __expf(fminf(bf2f(ku[jj]), 30.f));
            ls += ev;
            afu[jj] = f2bf(ev);
        }
        bf16x8 af = __builtin_bit_cast(bf16x8, afu);
#pragma unroll
        for (int di = 0; di < 4; ++di) {
            bf16x8 bfv = *(const bf16x8*)&vb[(size_t)(di * 16 + l15) * NN + n0];
            acc[di] = __builtin_amdgcn_mfma_f32_16x16x32_bf16(af, bfv, acc[di], 0, 0, 0);
        }
    }
    ls += __shfl_xor(ls, 16);
    ls += __shfl_xor(ls, 32);
    if (quad == 0) atomicAdd(&lsum[(size_t)bh * 64 + cb + l15], ls);

    const int c = cb + quad * 4;
#pragma unroll
    for (int di = 0; di < 4; ++di) {
        int d = di * 16 + l15;
#pragma unroll
        for (int r = 0; r < 4; ++r)
            atomicAdd(&ctxT[((size_t)bh * 64 + d) * 64 + c + r], acc[di][r]);
    }
}

// W_eff[b][o][h*64+c] = (1/l_c) * sum_d wout[o][h*64+d]*ctxT[b][h][d][c]
__global__ __launch_bounds__(256) void k_weff(const float* __restrict__ wout,
                                              const float* __restrict__ ctxT,
                                              const float* __restrict__ lsum,
                                              u16* __restrict__ weff) {
    int idx = blockIdx.x * 256 + threadIdx.x;   // 16*512*512
    int b = idx >> 18;
    int o = (idx >> 9) & 511;
    int hc = idx & 511;
    int h = hc >> 6, c = hc & 63;
    const float* wr = wout + o * 512 + h * 64;
    const float* cr = ctxT + ((size_t)b * 8 + h) * 4096 + c;
    float s = 0.f;
#pragma unroll
    for (int d = 0; d < 64; ++d) s += wr[d] * cr[d * 64];
    s *= 1.0f / lsum[((size_t)b * 8 + h) * 64 + c];
    weff[idx] = f2bf(s);
}

// ---------------- GEMM2: Y_b = W_eff_b(512x512) @ Q_b + b_out -----------------
// Epilogue: two 128-row f32 LDS halves -> 1KB-contiguous dwordx4 stores, bias fused.
__global__ __launch_bounds__(512, 2) void k_gemm2(
        const u16* __restrict__ weff, const u16* __restrict__ qt,
        const float* __restrict__ bout, float* __restrict__ y) {
    __shared__ __align__(16) u16 smem[65536];   // 128 KiB
    const int gid = blockIdx.x;                 // 512 blocks = 8 XCD * 64
    const int u = (gid & 7) * 64 + (gid >> 3);
    const int mt = u & 1;
    const int bn = u >> 1;
    const int b = bn >> 4;
    const int nt = bn & 15;
    const int t = threadIdx.x;
    const int lane = t & 63, w = t >> 6;
    const int l15 = lane & 15, quad = lane >> 4;

    f32x4 acc[2][2][4][2] = {};
    gemm256_core(smem, weff + (size_t)b * 512 * 512 + (size_t)(mt * 256) * CD,
                 qt + ((size_t)b * NN + nt * 256) * CD, acc);

    float* fsm = (float*)smem;                  // [128][256] f32 per half
    const int g = t & 63;
    for (int qm = 0; qm < 2; ++qm) {
        if (qm) __syncthreads();                // WAR: half-0 reads done before overwrite
#pragma unroll
        for (int mi = 0; mi < 4; ++mi) {
            const int ol = (w >> 2) * 64 + mi * 16 + quad * 4;
#pragma unroll
            for (int qn = 0; qn < 2; ++qn)
#pragma unroll
            for (int ni = 0; ni < 2; ++ni) {
                const int nl = qn * 128 + (w & 3) * 32 + ni * 16 + l15;
                f32x4 v = acc[qm][qn][mi][ni];
#pragma unroll
                for (int r = 0; r < 4; ++r) {
                    const int o = ol + r;
                    fsm[o * 256 + (nl ^ ((o & 7) << 2))] = v[r];
                }
            }
        }
        __syncthreads();
#pragma unroll 4
        for (int i = 0; i < 16; ++i) {
            const int o2 = i * 8 + (t >> 6);
            float4 pv = *(const float4*)&fsm[o2 * 256 + ((g * 4) ^ ((o2 & 7) << 2))];
            const int og = mt * 256 + qm * 128 + o2;
            const float bb = bout[og];
            pv.x += bb; pv.y += bb; pv.z += bb; pv.w += bb;
            *(float4*)&y[((size_t)(b * 512 + og)) * NN + nt * 256 + g * 4] = pv;
        }
    }
}

extern "C" void kernel_launch(void* const* d_in, const int* in_sizes, int n_in,
                              void* d_out, int out_size, void* d_ws, size_t ws_size,
                              hipStream_t stream) {
    const float* x    = (const float*)d_in[0];
    const float* wqkv = (const float*)d_in[1];
    const float* wout = (const float*)d_in[2];
    const float* bout = (const float*)d_in[3];
    float* y = (float*)d_out;

    char* ws = (char*)d_ws;
    u16*   xt   = (u16*)(ws);                       //  67,108,864  xt[b][n][c] bf16
    u16*   wqb  = (u16*)(ws + 67108864);            //   1,572,864  wqkv bf16
    u16*   qt   = (u16*)(ws + 68681728);            //  67,108,864  Qt[b][n][c] bf16
    u16*   kbuf = (u16*)(ws + 135790592);           //  67,108,864  K raw [b*512][n]
    u16*   vbuf = (u16*)(ws + 202899456);           //  67,108,864  V [b*512][n]
    float* ctxT = (float*)(ws + 270008320);         //   2,097,152  contextT fp32 (unnorm)
    float* lsum = (float*)(ws + 272105472);         //      32,768  row sums
    u16*   weff = (u16*)(ws + 272138240);           //   8,388,608  W_eff bf16

    hipMemsetAsync(ctxT, 0, 2097152 + 32768, stream);  // ctxT + lsum contiguous

    k_convert<<<(O3 * CD + 255) / 256, 256, 0, stream>>>(wqkv, wqb, O3 * CD);
    k_transpose_x<<<dim3(64 * 8, NB), 256, 0, stream>>>(x, xt);
    k_gemm1<<<1536, 512, 0, stream>>>(wqb, xt, qt, kbuf, vbuf);
    k_ctx<<<dim3(4, NB * 8), 256, 0, stream>>>(kbuf, vbuf, ctxT, lsum);
    k_weff<<<(NB * 512 * 512) / 256, 256, 0, stream>>>(wout, ctxT, lsum, weff);
    k_gemm2<<<512, 512, 0, stream>>>(weff, qt, bout, y);
}

// Round 3
// 517.339 us; speedup vs baseline: 1.0480x; 1.0480x over previous
//
#include <hip/hip_runtime.h>
#include <string.h>

typedef __bf16 bf16x8 __attribute__((ext_vector_type(8)));
typedef float f32x4 __attribute__((ext_vector_type(4)));
typedef unsigned short u16;
typedef u16 u16x8 __attribute__((ext_vector_type(8)));

#define NB 16     // batch
#define CD 512    // channels
#define NN 4096   // hw
#define O3 1536   // 3*hidden

__device__ __forceinline__ u16 f2bf(float f) {
    union { float f; unsigned int u; } v; v.f = f;
    unsigned int r = v.u + 0x7fffu + ((v.u >> 16) & 1u);
    return (u16)(r >> 16);
}
__device__ __forceinline__ float bf2f(u16 s) {
    union { unsigned int u; float f; } v; v.u = ((unsigned int)s) << 16;
    return v.f;
}

__device__ __forceinline__ void gl2lds16(const u16* g, u16* l) {
    __builtin_amdgcn_global_load_lds(
        (const void __attribute__((address_space(1)))*)g,
        (void __attribute__((address_space(3)))*)l,
        16, 0, 0);
}

// ---------------- convert w_qkv fp32 -> bf16 (row-major [1536][512]) ----------
__global__ void k_convert(const float* __restrict__ in, u16* __restrict__ out, int n) {
    int i = blockIdx.x * 256 + threadIdx.x;
    if (i < n) out[i] = f2bf(in[i]);
}

// ---------------- transpose x[b][c][n] fp32 -> xt[b][n][c] bf16, 64x64 tiles --
__global__ __launch_bounds__(256) void k_transpose_x(const float* __restrict__ x,
                                                     u16* __restrict__ xt) {
    __shared__ float tile[64][65];
    const int b = blockIdx.y;
    const int ntile = blockIdx.x & 63;   // 4096/64
    const int ctile = blockIdx.x >> 6;   // 512/64
    const int t = threadIdx.x;
    const int r = t >> 2;                // 0..63 (row)
    const int q = t & 3;                 // 4 threads per row

    const float* xb = x + ((size_t)b * CD + ctile * 64 + r) * NN + ntile * 64;
#pragma unroll
    for (int j = 0; j < 4; ++j) {
        float4 v = *(const float4*)&xb[q * 16 + j * 4];
        tile[r][q * 16 + j * 4 + 0] = v.x;
        tile[r][q * 16 + j * 4 + 1] = v.y;
        tile[r][q * 16 + j * 4 + 2] = v.z;
        tile[r][q * 16 + j * 4 + 3] = v.w;
    }
    __syncthreads();
    u16* xtb = xt + ((size_t)b * NN + ntile * 64 + r) * CD + ctile * 64 + q * 16;
    u16x8 o0, o1;
#pragma unroll
    for (int j = 0; j < 8; ++j) {
        o0[j] = f2bf(tile[q * 16 + j][r]);
        o1[j] = f2bf(tile[q * 16 + 8 + j][r]);
    }
    *(u16x8*)&xtb[0] = o0;
    *(u16x8*)&xtb[8] = o1;
}

// =============================================================================
// 256x256 bf16 GEMM core — pipelined-read 4-phase schedule.
// vs R1: ONE barrier per phase (4/K-tile, was 8); NO lgkmcnt(0) drain (compiler
// emits fine-grained per-operand waits); bb1/bb0 LDS reads issued one phase
// ahead into free registers so they hide under MFMA. Register peak unchanged.
//
// Steady-state in-flight vmem invariant entering p0(kt): {A0,B0(kt+1)} = 4.
//   p0: +stage B1,A1(kt+1) -> 8    p1: +stage A0(kt+2) -> 10
//   p2: +stage B0(kt+2) -> 12; vmcnt(4) completes tile kt+1 (oldest 8),
//       leaves {A0,B0(kt+2)} = 4.  Never drains to 0 until kt==6.
// WAR safety: every staged buffer's previous readers completed their ds_read
// before their own MFMA's lgkm wait, which precedes >=1 intervening barrier.
// =============================================================================

__device__ __forceinline__ void lda8(const u16* p, bf16x8 (&aa)[4][2],
                                     int aoff, int sw0, int sw1) {
#pragma unroll
    for (int mi = 0; mi < 4; ++mi) {
        aa[mi][0] = *(const bf16x8*)&p[aoff + mi * 1024 + sw0];
        aa[mi][1] = *(const bf16x8*)&p[aoff + mi * 1024 + sw1];
    }
}

__device__ __forceinline__ void ldb4(const u16* p, bf16x8 (&bb)[2][2],
                                     int boff, int sw0, int sw1) {
#pragma unroll
    for (int ni = 0; ni < 2; ++ni) {
        bb[ni][0] = *(const bf16x8*)&p[boff + ni * 1024 + sw0];
        bb[ni][1] = *(const bf16x8*)&p[boff + ni * 1024 + sw1];
    }
}

__device__ __forceinline__ void mfma16(bf16x8 (&aa)[4][2], bf16x8 (&bb)[2][2],
                                       f32x4 (&ac)[4][2]) {
    __builtin_amdgcn_s_setprio(1);
#pragma unroll
    for (int mi = 0; mi < 4; ++mi)
#pragma unroll
        for (int ni = 0; ni < 2; ++ni) {
            ac[mi][ni] = __builtin_amdgcn_mfma_f32_16x16x32_bf16(
                aa[mi][0], bb[ni][0], ac[mi][ni], 0, 0, 0);
            ac[mi][ni] = __builtin_amdgcn_mfma_f32_16x16x32_bf16(
                aa[mi][1], bb[ni][1], ac[mi][ni], 0, 0, 0);
        }
    __builtin_amdgcn_s_setprio(0);
}

#define BAR() do { \
    asm volatile("" ::: "memory"); \
    __builtin_amdgcn_s_barrier(); \
    asm volatile("" ::: "memory"); \
} while (0)

__device__ __forceinline__ void gemm256_core(u16* __restrict__ smem,
                                             const u16* __restrict__ Abase,
                                             const u16* __restrict__ Bbase,
                                             f32x4 (&acc)[2][2][4][2]) {
    const int t = threadIdx.x;
    const int lane = t & 63;
    const int w = t >> 6;
    const int l15 = lane & 15, quad = lane >> 4;
    const int r0 = t >> 3;                       // staging row 0..63 (issue 0)
    const int sg = ((t & 7) ^ (r0 & 7)) * 8;     // pre-swizzled source k-offset (elems)
    const int aoff = ((w >> 2) * 64 + l15) * 64; // wave m-offset within quadrant half
    const int boff = ((w & 3) * 32 + l15) * 64;  // wave n-offset within quadrant half
    const int sw0 = ((0 + quad) ^ (l15 & 7)) * 8;  // swizzled read slot, kstep 0
    const int sw1 = ((4 + quad) ^ (l15 & 7)) * 8;  // swizzled read slot, kstep 1

    auto ldsAt = [&](int s, int op, int half) -> u16* {
        return smem + (size_t)(((s * 2 + op) * 2 + half) * 8192);
    };

    auto stage = [&](int op, int half, int tau) {
        const u16* s = (op ? Bbase : Abase)
                       + (size_t)(half * 128 + r0) * CD + tau * 64 + sg;
        u16* d = ldsAt(tau & 1, op, half) + t * 8;
        gl2lds16(s, d);                          // rows 0..63 of the half
        gl2lds16(s + (size_t)64 * CD, d + 4096); // rows 64..127
    };

    // prologue: tile0 fully (A0,B0,B1,A1) + A0,B0 of tile1
    stage(0, 0, 0); stage(1, 0, 0); stage(1, 1, 0); stage(0, 1, 0);
    stage(0, 0, 1); stage(1, 0, 1);
    asm volatile("s_waitcnt vmcnt(4)" ::: "memory");  // tile0 complete, A0/B0(1) in flight
    BAR();

    bf16x8 aa[4][2], bb0[2][2], bb1[2][2];
    ldb4(ldsAt(0, 1, 0), bb0, boff, sw0, sw1);   // preload B0(tile0)

    for (int kt = 0; kt < 8; ++kt) {
        const int s = kt & 1;
        // ---- p0: Q(0,0) = A0 x B0. In-phase A0 (fine-grained wait), pipelined B1.
        lda8(ldsAt(s, 0, 0), aa, aoff, sw0, sw1);
        ldb4(ldsAt(s, 1, 1), bb1, boff, sw0, sw1);
        if (kt <= 6) { stage(1, 1, kt + 1); stage(0, 1, kt + 1); }
        mfma16(aa, bb0, acc[0][0]);
        BAR();
        // ---- p1: Q(0,1) = A0 x B1 (all operands resident)
        if (kt <= 5) stage(0, 0, kt + 2);
        mfma16(aa, bb1, acc[0][1]);
        BAR();
        // ---- p2: Q(1,0) = A1 x B0. In-phase A1 (fine-grained wait).
        lda8(ldsAt(s, 0, 1), aa, aoff, sw0, sw1);
        if (kt <= 5) stage(1, 0, kt + 2);
        mfma16(aa, bb0, acc[1][0]);
        if (kt <= 5)      asm volatile("s_waitcnt vmcnt(4)" ::: "memory"); // tile kt+1 ready
        else if (kt == 6) asm volatile("s_waitcnt vmcnt(0)" ::: "memory"); // final drain
        BAR();
        // ---- p3: Q(1,1) = A1 x B1. Pipelined B0' of next tile into free bb0.
        if (kt <= 6) ldb4(ldsAt(s ^ 1, 1, 0), bb0, boff, sw0, sw1);
        mfma16(aa, bb1, acc[1][1]);
        BAR();
    }
    // all LDS reads/writes complete; callers may reuse smem.
}

// ---------------- GEMM1: qkv = Wqkv(1536x512) @ X_b(512x4096) -----------------
// m-tiles of 256 align with sections: mt 0-1 -> Q, 2-3 -> K, 4-5 -> V.
__global__ __launch_bounds__(512, 2) void k_gemm1(
        const u16* __restrict__ A, const u16* __restrict__ Bt,
        u16* __restrict__ qt, u16* __restrict__ kbuf, u16* __restrict__ vbuf) {
    __shared__ __align__(16) u16 smem[65536];   // 128 KiB loop double-buffer
    const int gid = blockIdx.x;                 // 1536 blocks = 8 XCD * 192
    const int u = (gid & 7) * 192 + (gid >> 3);
    const int mt = u % 6;                       // 6 consecutive share B-panel on one XCD
    const int bn = u / 6;
    const int b = bn >> 4;
    const int nt = bn & 15;
    const int t = threadIdx.x;
    const int lane = t & 63, w = t >> 6;
    const int l15 = lane & 15, quad = lane >> 4;

    f32x4 acc[2][2][4][2] = {};
    gemm256_core(smem, A + (size_t)(mt * 256) * CD,
                 Bt + ((size_t)b * NN + nt * 256) * CD, acc);

    const int sec = mt >> 1;                    // 0=Q 1=K 2=V
    const int lrb = mt * 256 - sec * 512;
#pragma unroll
    for (int qm = 0; qm < 2; ++qm)
#pragma unroll
    for (int mi = 0; mi < 4; ++mi) {
        const int ml = qm * 128 + (w >> 2) * 64 + mi * 16 + quad * 4;
#pragma unroll
        for (int qn = 0; qn < 2; ++qn)
#pragma unroll
        for (int ni = 0; ni < 2; ++ni) {
            const int n = nt * 256 + qn * 128 + (w & 3) * 32 + ni * 16 + l15;
            f32x4 v = acc[qm][qn][mi][ni];
            if (sec == 0) {
                ushort4 pk;
                pk.x = f2bf(v[0]); pk.y = f2bf(v[1]);
                pk.z = f2bf(v[2]); pk.w = f2bf(v[3]);
                *(ushort4*)&qt[((size_t)b * NN + n) * CD + mt * 256 + ml] = pk;
            } else {
                u16* dst = (sec == 1) ? kbuf : vbuf;
#pragma unroll
                for (int r = 0; r < 4; ++r)
                    dst[((size_t)(b * 512 + lrb + ml + r)) * NN + n] = f2bf(v[r]);
            }
        }
    }
}

// -------- fused exp + context: ctxT[bh][d][c] += sum_n exp(K[c][n]) V[d][n] ---
__global__ __launch_bounds__(256) void k_ctx(const u16* __restrict__ kbuf,
                                             const u16* __restrict__ vbuf,
                                             float* __restrict__ ctxT,
                                             float* __restrict__ lsum) {
    const int bh = blockIdx.y;           // 0..127
    const int chunk = blockIdx.x;        // 0..3, 1024 n each
    const int t = threadIdx.x, lane = t & 63, w = t >> 6;
    const int l15 = lane & 15, quad = lane >> 4;
    const int cb = w * 16;               // wave's 16 c-rows

    const u16* krow = kbuf + (size_t)(bh * 64 + cb + l15) * NN;
    const u16* vb   = vbuf + (size_t)bh * 64 * NN;

    f32x4 acc[4] = {};
    float ls = 0.f;
    for (int i = 0; i < 32; ++i) {
        int n0 = chunk * 1024 + i * 32 + quad * 8;
        u16x8 ku = *(const u16x8*)&krow[n0];
        u16x8 afu;
#pragma unroll
        for (int jj = 0; jj < 8; ++jj) {
            float ev = __expf(fminf(bf2f(ku[jj]), 30.f));
            ls += ev;
            afu[jj] = f2bf(ev);
        }
        bf16x8 af = __builtin_bit_cast(bf16x8, afu);
#pragma unroll
        for (int di = 0; di < 4; ++di) {
            bf16x8 bfv = *(const bf16x8*)&vb[(size_t)(di * 16 + l15) * NN + n0];
            acc[di] = __builtin_amdgcn_mfma_f32_16x16x32_bf16(af, bfv, acc[di], 0, 0, 0);
        }
    }
    ls += __shfl_xor(ls, 16);
    ls += __shfl_xor(ls, 32);
    if (quad == 0) atomicAdd(&lsum[(size_t)bh * 64 + cb + l15], ls);

    const int c = cb + quad * 4;
#pragma unroll
    for (int di = 0; di < 4; ++di) {
        int d = di * 16 + l15;
#pragma unroll
        for (int r = 0; r < 4; ++r)
            atomicAdd(&ctxT[((size_t)bh * 64 + d) * 64 + c + r], acc[di][r]);
    }
}

// W_eff[b][o][h*64+c] = (1/l_c) * sum_d wout[o][h*64+d]*ctxT[b][h][d][c]
__global__ __launch_bounds__(256) void k_weff(const float* __restrict__ wout,
                                              const float* __restrict__ ctxT,
                                              const float* __restrict__ lsum,
                                              u16* __restrict__ weff) {
    int idx = blockIdx.x * 256 + threadIdx.x;   // 16*512*512
    int b = idx >> 18;
    int o = (idx >> 9) & 511;
    int hc = idx & 511;
    int h = hc >> 6, c = hc & 63;
    const float* wr = wout + o * 512 + h * 64;
    const float* cr = ctxT + ((size_t)b * 8 + h) * 4096 + c;
    float s = 0.f;
#pragma unroll
    for (int d = 0; d < 64; ++d) s += wr[d] * cr[d * 64];
    s *= 1.0f / lsum[((size_t)b * 8 + h) * 64 + c];
    weff[idx] = f2bf(s);
}

// ---------------- GEMM2: Y_b = W_eff_b(512x512) @ Q_b + b_out -----------------
__global__ __launch_bounds__(512, 2) void k_gemm2(
        const u16* __restrict__ weff, const u16* __restrict__ qt,
        const float* __restrict__ bout, float* __restrict__ y) {
    __shared__ __align__(16) u16 smem[65536];   // 128 KiB
    const int gid = blockIdx.x;                 // 512 blocks = 8 XCD * 64
    const int u = (gid & 7) * 64 + (gid >> 3);
    const int mt = u & 1;
    const int bn = u >> 1;
    const int b = bn >> 4;
    const int nt = bn & 15;
    const int t = threadIdx.x;
    const int lane = t & 63, w = t >> 6;
    const int l15 = lane & 15, quad = lane >> 4;

    f32x4 acc[2][2][4][2] = {};
    gemm256_core(smem, weff + (size_t)b * 512 * 512 + (size_t)(mt * 256) * CD,
                 qt + ((size_t)b * NN + nt * 256) * CD, acc);

#pragma unroll
    for (int qm = 0; qm < 2; ++qm)
#pragma unroll
    for (int mi = 0; mi < 4; ++mi) {
        const int o = mt * 256 + qm * 128 + (w >> 2) * 64 + mi * 16 + quad * 4;
#pragma unroll
        for (int qn = 0; qn < 2; ++qn)
#pragma unroll
        for (int ni = 0; ni < 2; ++ni) {
            const int n = nt * 256 + qn * 128 + (w & 3) * 32 + ni * 16 + l15;
            f32x4 v = acc[qm][qn][mi][ni];
#pragma unroll
            for (int r = 0; r < 4; ++r)
                y[((size_t)(b * 512 + o + r)) * NN + n] = v[r] + bout[o + r];
        }
    }
}

extern "C" void kernel_launch(void* const* d_in, const int* in_sizes, int n_in,
                              void* d_out, int out_size, void* d_ws, size_t ws_size,
                              hipStream_t stream) {
    const float* x    = (const float*)d_in[0];
    const float* wqkv = (const float*)d_in[1];
    const float* wout = (const float*)d_in[2];
    const float* bout = (const float*)d_in[3];
    float* y = (float*)d_out;

    char* ws = (char*)d_ws;
    u16*   xt   = (u16*)(ws);                       //  67,108,864  xt[b][n][c] bf16
    u16*   wqb  = (u16*)(ws + 67108864);            //   1,572,864  wqkv bf16
    u16*   qt   = (u16*)(ws + 68681728);            //  67,108,864  Qt[b][n][c] bf16
    u16*   kbuf = (u16*)(ws + 135790592);           //  67,108,864  K raw [b*512][n]
    u16*   vbuf = (u16*)(ws + 202899456);           //  67,108,864  V [b*512][n]
    float* ctxT = (float*)(ws + 270008320);         //   2,097,152  contextT fp32 (unnorm)
    float* lsum = (float*)(ws + 272105472);         //      32,768  row sums
    u16*   weff = (u16*)(ws + 272138240);           //   8,388,608  W_eff bf16

    hipMemsetAsync(ctxT, 0, 2097152 + 32768, stream);  // ctxT + lsum contiguous

    k_convert<<<(O3 * CD + 255) / 256, 256, 0, stream>>>(wqkv, wqb, O3 * CD);
    k_transpose_x<<<dim3(64 * 8, NB), 256, 0, stream>>>(x, xt);
    k_gemm1<<<1536, 512, 0, stream>>>(wqb, xt, qt, kbuf, vbuf);
    k_ctx<<<dim3(4, NB * 8), 256, 0, stream>>>(kbuf, vbuf, ctxT, lsum);
    k_weff<<<(NB * 512 * 512) / 256, 256, 0, stream>>>(wout, ctxT, lsum, weff);
    k_gemm2<<<512, 512, 0, stream>>>(weff, qt, bout, y);
}